// Round 1
// 1226.010 us; speedup vs baseline: 1.2907x; 1.2907x over previous
//
#include <hip/hip_runtime.h>

#define ND    20000
#define NPn   10000
#define Bsz   4096
#define DE    320000
#define PEe   160000
#define FEAT  3372

#define ENC_OFF  4096ull
#define DEC_OFF  1052672ull              /* 4096*257 */
#define FEAT_OFF 14864384ull             /* DEC_OFF + 4096*3372 */

typedef unsigned short u16;
typedef unsigned int   u32;
typedef __bf16 bf16x8 __attribute__((ext_vector_type(8)));
typedef float  f32x4  __attribute__((ext_vector_type(4)));

__device__ __forceinline__ float bf2f(u16 u) {
    u32 v = ((u32)u) << 16;
    return __builtin_bit_cast(float, v);
}
__device__ __forceinline__ u16 f2bf(float f) {
    u32 x = __builtin_bit_cast(u32, f);
    x += 0x7fffu + ((x >> 16) & 1u);
    return (u16)(x >> 16);
}
__device__ __forceinline__ float lrelu(float x) { return x > 0.f ? x : 0.01f * x; }

// flag-driven scalar load/store (wave-uniform flag)
__device__ __forceinline__ float ldv(const void* p, size_t i, int f32) {
    return f32 ? ((const float*)p)[i] : bf2f(((const u16*)p)[i]);
}
__device__ __forceinline__ void stv(void* p, size_t i, int f32, float v) {
    if (f32) ((float*)p)[i] = v; else ((u16*)p)[i] = f2bf(v);
}

// ---------------------------------------------------------------------------
// dtype detect: d_edge_weight is uniform[0,1). fp32 -> low u16 of each word is
// random mantissa bits (>0x4200 with p=.74). bf16 pairs -> both halves <=0x3F80.
// ---------------------------------------------------------------------------
__global__ void detect_dtype(const u32* __restrict__ ew, int* __restrict__ flag)
{
    int t = threadIdx.x, bad = 0;
    for (int i = t; i < 256; i += 64)
        if ((ew[i] & 0xffffu) > 0x4200u) bad = 1;
    unsigned long long m = __ballot(bad);
    if (t == 0) *flag = (m != 0ull) ? 1 : 0;   // 1 = fp32 inputs
}

// ---------------------------------------------------------------------------
// W[K,N] -> Th[N,Kp], Tl[N,Kp]  (bf16 hi/lo split planes, zero K-pad)
// ---------------------------------------------------------------------------
__global__ __launch_bounds__(256) void transpose_split(const void* __restrict__ W,
                                                       u16* __restrict__ Th,
                                                       u16* __restrict__ Tl,
                                                       int K, int N, int Kp,
                                                       const int* __restrict__ flagp)
{
    const int f32 = *flagp;
    __shared__ float tile[32][33];
    const int k0 = blockIdx.x * 32, n0 = blockIdx.y * 32;
    const int tx = threadIdx.x & 31, ty = threadIdx.x >> 5;
    for (int i = 0; i < 4; ++i) {
        int k = k0 + ty + 8 * i, n = n0 + tx;
        float v = 0.f;
        if (k < K && n < N) v = ldv(W, (size_t)k * N + n, f32);
        tile[ty + 8 * i][tx] = v;
    }
    __syncthreads();
    for (int i = 0; i < 4; ++i) {
        int n = n0 + ty + 8 * i, k = k0 + tx;
        if (n < N && k < Kp) {
            float v = tile[tx][ty + 8 * i];
            u16 h = f2bf(v);
            Th[(size_t)n * Kp + k] = h;
            Tl[(size_t)n * Kp + k] = f2bf(v - bf2f(h));
        }
    }
}

// ---------------------------------------------------------------------------
// Graph prep
// ---------------------------------------------------------------------------
__global__ void deg_accum(const int* __restrict__ ei, const void* __restrict__ ew,
                          float* __restrict__ deg, int E, const int* __restrict__ flagp)
{
    const int f32 = *flagp;
    int e = blockIdx.x * blockDim.x + threadIdx.x;
    if (e >= E) return;
    atomicAdd(&deg[ei[E + e]], ldv(ew, e, f32));
}

__global__ void dinv_kernel(float* __restrict__ deg, int n)
{
    int i = blockIdx.x * blockDim.x + threadIdx.x;
    if (i >= n) return;
    deg[i] = rsqrtf(deg[i] + 1.0f);   // +1 self-loop; always > 0
}

__global__ void csr_count(const int* __restrict__ ei, int* __restrict__ cnt, int E)
{
    int e = blockIdx.x * blockDim.x + threadIdx.x;
    if (e >= E) return;
    atomicAdd(&cnt[ei[E + e]], 1);
}

__global__ __launch_bounds__(256) void scan_kernel(const int* __restrict__ cnt,
                                                   int* __restrict__ offs,
                                                   int* __restrict__ cur, int n)
{
    __shared__ int tot[256];
    __shared__ int pref[257];
    const int t = threadIdx.x;
    const int chunk = (n + 255) / 256;
    const int s0 = t * chunk;
    const int s1 = (s0 + chunk < n) ? (s0 + chunk) : n;
    int s = 0;
    for (int i = s0; i < s1; ++i) s += cnt[i];
    tot[t] = s;
    __syncthreads();
    if (t == 0) {
        int run = 0;
        for (int i = 0; i < 256; ++i) { pref[i] = run; run += tot[i]; }
        pref[256] = run;
    }
    __syncthreads();
    int run = pref[t];
    for (int i = s0; i < s1; ++i) { offs[i] = run; cur[i] = run; run += cnt[i]; }
    if (t == 255) offs[n] = pref[256];
}

__global__ void csr_fill(const int* __restrict__ ei, const void* __restrict__ ew,
                         int* __restrict__ cur, int* __restrict__ crow,
                         float* __restrict__ cw, int E, const int* __restrict__ flagp)
{
    const int f32 = *flagp;
    int e = blockIdx.x * blockDim.x + threadIdx.x;
    if (e >= E) return;
    int c = ei[E + e];
    int p = atomicAdd(&cur[c], 1);
    crow[p] = ei[e];
    cw[p]   = ldv(ew, e, f32);
}

// ---------------------------------------------------------------------------
// Per-batch-row aggregation of raw X (commutes with @W):
//   agg[b] = dinv[c]^2 * X[c] + sum_e dinv[r]*w*dinv[c] * X[r],  c = idx[b]
// ---------------------------------------------------------------------------
__global__ __launch_bounds__(256) void aggregate(const void* __restrict__ X, int ldx,
                                                 int ncols,
                                                 const int* __restrict__ bidx,
                                                 const float* __restrict__ dinv,
                                                 const int* __restrict__ offs,
                                                 const int* __restrict__ crow,
                                                 const float* __restrict__ cw,
                                                 const int* __restrict__ flagp,
                                                 float* __restrict__ out, int ldo)
{
    const int f32 = *flagp;
    const int b = blockIdx.x, t = threadIdx.x;
    const int node = bidx[b];
    const int nch = ncols >> 2;            // ncols divisible by 4 (1024, 2812)
    const float dc = dinv[node];
    float acc[3][4];
#pragma unroll
    for (int i = 0; i < 3; ++i)
        for (int j = 0; j < 4; ++j) acc[i][j] = 0.f;

    {   // self loop (weight 1)
        const float sw = dc * dc;
        const size_t rb = (size_t)node * ldx;
#pragma unroll
        for (int i = 0; i < 3; ++i) {
            int c = t + 256 * i;
            if (c < nch) {
                float v[4];
                if (f32) {
                    float4 x = *(const float4*)((const float*)X + rb + 4 * c);
                    v[0] = x.x; v[1] = x.y; v[2] = x.z; v[3] = x.w;
                } else {
                    uint2 x = *(const uint2*)((const u16*)X + rb + 4 * c);
                    v[0] = bf2f((u16)(x.x & 0xffffu)); v[1] = bf2f((u16)(x.x >> 16));
                    v[2] = bf2f((u16)(x.y & 0xffffu)); v[3] = bf2f((u16)(x.y >> 16));
                }
                for (int j = 0; j < 4; ++j) acc[i][j] += v[j] * sw;
            }
        }
    }
    const int e1 = offs[node + 1];
    for (int e = offs[node]; e < e1; ++e) {
        const int r = crow[e];
        const float nrm = dinv[r] * cw[e] * dc;
        const size_t rb = (size_t)r * ldx;
#pragma unroll
        for (int i = 0; i < 3; ++i) {
            int c = t + 256 * i;
            if (c < nch) {
                float v[4];
                if (f32) {
                    float4 x = *(const float4*)((const float*)X + rb + 4 * c);
                    v[0] = x.x; v[1] = x.y; v[2] = x.z; v[3] = x.w;
                } else {
                    uint2 x = *(const uint2*)((const u16*)X + rb + 4 * c);
                    v[0] = bf2f((u16)(x.x & 0xffffu)); v[1] = bf2f((u16)(x.x >> 16));
                    v[2] = bf2f((u16)(x.y & 0xffffu)); v[3] = bf2f((u16)(x.y >> 16));
                }
                for (int j = 0; j < 4; ++j) acc[i][j] += v[j] * nrm;
            }
        }
    }
    const size_t ob = (size_t)b * ldo;
#pragma unroll
    for (int i = 0; i < 3; ++i) {
        int c = t + 256 * i;
        if (c < nch) {
            float4 v; v.x = acc[i][0]; v.y = acc[i][1]; v.z = acc[i][2]; v.w = acc[i][3];
            *(float4*)(out + ob + 4 * c) = v;
        }
    }
    if (t == 0)
        for (int j = ncols; j < ldo; ++j) out[ob + j] = 0.f;   // zero K-pad
}

// ---------------------------------------------------------------------------
// Split-bf16 MFMA GEMM: C[M,N] = A[M,K] @ (Bh+Bl)[N,Kp]^T  (+bias, +leaky)
// A split to hi/lo at staging; 3-term: Ah*Bh + Ah*Bl + Al*Bh  (~2^-16 rel)
// amode/cmode: 0 = buffer is fp32 ws; 1 = buffer dtype follows *flagp
//
// v2: 512 threads (8 waves = 2/SIMD at 1 block/CU), software-pipelined
// staging: issue next K-tile's global loads into regs BEFORE ds_read+MFMA,
// convert+commit to LDS after the post-MFMA barrier (T14 async-STAGE split).
// ---------------------------------------------------------------------------
__global__ __launch_bounds__(512, 4) void gemm_split(
        const void* __restrict__ A, int amode, unsigned long long a_off, int lda,
        const u16* __restrict__ Bh, const u16* __restrict__ Bl, int ldb,
        void* __restrict__ C, int cmode, unsigned long long c_off, int ldc,
        const void* __restrict__ bias, int M, int N, int K, int Kp,
        int do_leaky, const int* __restrict__ flagp)
{
    const int flag = *flagp;
    const int af32 = amode ? flag : 1;
    const int cf32 = cmode ? flag : 1;
    __shared__ u16 Ash[128 * 40], Asl[128 * 40], Bsh[128 * 40], Bsl[128 * 40];
    const int tid = threadIdx.x;
    const int m0 = blockIdx.y * 128, n0 = blockIdx.x * 128;
    const int w = tid >> 6, lane = tid & 63;
    const int wy = w >> 1, wx = w & 1, lr = lane & 15, q = lane >> 4;
    f32x4 acc[2][4] = {};
    const int rs = tid >> 2, cs = tid & 3;   // row 0..127, 8-col chunk 0..3

    const int gm = m0 + rs;                  // A row this thread stages
    const int gn = n0 + rs;                  // B row this thread stages

    // staged registers (next K-tile, in flight across MFMA phase)
    float av[8];
    uint2 vbh0, vbh1, vbl0, vbl1;

    auto issue = [&](int k0) {
        const int kk = k0 + cs * 8;
        // ---- A (fp32 or bf16 source) ----
        if (gm < M) {
            size_t ro = (size_t)a_off + (size_t)gm * lda;
            if (kk + 8 <= K) {
                if (af32) {
                    const float* ap = (const float*)A + ro + kk;
                    float4 x = *(const float4*)ap, y = *(const float4*)(ap + 4);
                    av[0]=x.x; av[1]=x.y; av[2]=x.z; av[3]=x.w;
                    av[4]=y.x; av[5]=y.y; av[6]=y.z; av[7]=y.w;
                } else {
                    const u16* ap = (const u16*)A + ro + kk;
                    uint2 x = *(const uint2*)ap, y = *(const uint2*)(ap + 4);
                    u32 wd[4] = {x.x, x.y, y.x, y.y};
#pragma unroll
                    for (int i = 0; i < 4; ++i) {
                        av[2*i]   = bf2f((u16)(wd[i] & 0xffffu));
                        av[2*i+1] = bf2f((u16)(wd[i] >> 16));
                    }
                }
            } else {
#pragma unroll
                for (int i = 0; i < 8; ++i)
                    av[i] = (kk + i < K)
                         ? (af32 ? ((const float*)A)[ro + kk + i]
                                 : bf2f(((const u16*)A)[ro + kk + i]))
                         : 0.f;
            }
        } else {
#pragma unroll
            for (int i = 0; i < 8; ++i) av[i] = 0.f;
        }
        // ---- B planes (already split bf16, Kp-padded) ----
        if (gn < N) {
            const u16* bp = Bh + (size_t)gn * ldb + kk;
            vbh0 = *(const uint2*)bp; vbh1 = *(const uint2*)(bp + 4);
            const u16* lp = Bl + (size_t)gn * ldb + kk;
            vbl0 = *(const uint2*)lp; vbl1 = *(const uint2*)(lp + 4);
        } else {
            vbh0 = {0,0}; vbh1 = {0,0}; vbl0 = {0,0}; vbl1 = {0,0};
        }
    };

    auto commit = [&]() {
        u16* dh = &Ash[rs * 40 + cs * 8];
        u16* dl = &Asl[rs * 40 + cs * 8];
#pragma unroll
        for (int i = 0; i < 8; ++i) {
            u16 h = f2bf(av[i]);
            dh[i] = h;
            dl[i] = f2bf(av[i] - bf2f(h));
        }
        *(uint2*)&Bsh[rs * 40 + cs * 8]     = vbh0;
        *(uint2*)&Bsh[rs * 40 + cs * 8 + 4] = vbh1;
        *(uint2*)&Bsl[rs * 40 + cs * 8]     = vbl0;
        *(uint2*)&Bsl[rs * 40 + cs * 8 + 4] = vbl1;
    };

    // prologue: stage tile 0
    issue(0);
    commit();
    __syncthreads();

    for (int k0 = 0; k0 < Kp; k0 += 32) {
        const int nxt = k0 + 32;
        // 1. issue next tile's global loads (ride across the MFMA phase)
        if (nxt < Kp) issue(nxt);
        // 2. ds_read fragments + MFMA on current tile
        bf16x8 bh[4], bl[4];
#pragma unroll
        for (int ni = 0; ni < 4; ++ni) {
            bh[ni] = *(const bf16x8*)&Bsh[(wx * 64 + ni * 16 + lr) * 40 + q * 8];
            bl[ni] = *(const bf16x8*)&Bsl[(wx * 64 + ni * 16 + lr) * 40 + q * 8];
        }
#pragma unroll
        for (int mi = 0; mi < 2; ++mi) {
            bf16x8 ah = *(const bf16x8*)&Ash[(wy * 32 + mi * 16 + lr) * 40 + q * 8];
            bf16x8 al = *(const bf16x8*)&Asl[(wy * 32 + mi * 16 + lr) * 40 + q * 8];
#pragma unroll
            for (int ni = 0; ni < 4; ++ni) {
                acc[mi][ni] = __builtin_amdgcn_mfma_f32_16x16x32_bf16(ah, bh[ni], acc[mi][ni], 0, 0, 0);
                acc[mi][ni] = __builtin_amdgcn_mfma_f32_16x16x32_bf16(ah, bl[ni], acc[mi][ni], 0, 0, 0);
                acc[mi][ni] = __builtin_amdgcn_mfma_f32_16x16x32_bf16(al, bh[ni], acc[mi][ni], 0, 0, 0);
            }
        }
        // 3. all waves done reading LDS, then overwrite with next tile
        __syncthreads();
        if (nxt < Kp) {
            commit();
            __syncthreads();
        }
    }

    // ---- epilogue: C/D layout col=lane&15, row=(lane>>4)*4+reg ----
#pragma unroll
    for (int mi = 0; mi < 2; ++mi)
#pragma unroll
        for (int r = 0; r < 4; ++r) {
            int gmr = m0 + wy * 32 + mi * 16 + q * 4 + r;
            if (gmr >= M) continue;
            size_t ro = (size_t)c_off + (size_t)gmr * ldc;
#pragma unroll
            for (int ni = 0; ni < 4; ++ni) {
                int gnc = n0 + wx * 64 + ni * 16 + lr;
                if (gnc >= N) continue;
                float v = acc[mi][ni][r];
                if (bias) v += ldv(bias, gnc, flag);
                if (do_leaky) v = lrelu(v);
                stv(C, ro + gnc, cf32, v);
            }
        }
}

// ---------------------------------------------------------------------------
// feature cols [0,1324) = [d_vecs | p_embeddings]
// ---------------------------------------------------------------------------
__global__ __launch_bounds__(256) void concat(const void* __restrict__ d_vecs,
                                              const void* __restrict__ p_emb,
                                              void* __restrict__ out,
                                              const int* __restrict__ flagp)
{
    const int f32 = *flagp;
    const int b = blockIdx.x;
    const size_t fb = FEAT_OFF + (size_t)b * FEAT;
    for (int j = threadIdx.x; j < 1324; j += 256) {
        float v = (j < 300) ? ldv(d_vecs, (size_t)b * 300 + j, f32)
                            : ldv(p_emb, (size_t)b * 1024 + (j - 300), f32);
        stv(out, fb + j, f32, v);
    }
}

// ---------------------------------------------------------------------------
// Head: h = enc@W1+b1 -> BN(eval) -> leaky -> @W2+b2 -> y
// ---------------------------------------------------------------------------
__global__ __launch_bounds__(128) void head(void* __restrict__ out,
                                            const void* __restrict__ W1,
                                            const void* __restrict__ b1,
                                            const void* __restrict__ g,
                                            const void* __restrict__ be,
                                            const void* __restrict__ mu,
                                            const void* __restrict__ vr,
                                            const void* __restrict__ W2,
                                            const void* __restrict__ b2,
                                            const int* __restrict__ flagp)
{
    const int f32 = *flagp;
    __shared__ float se[256];
    __shared__ float red[128];
    const int b = blockIdx.x, t = threadIdx.x;
    const size_t eb = ENC_OFF + (size_t)b * 256;
    se[t]       = ldv(out, eb + t, f32);
    se[t + 128] = ldv(out, eb + 128 + t, f32);
    __syncthreads();
    float acc = 0.f;
    for (int k = 0; k < 256; ++k) acc += se[k] * ldv(W1, (size_t)k * 128 + t, f32);
    acc += ldv(b1, t, f32);
    float bn = (acc - ldv(mu, t, f32)) * rsqrtf(ldv(vr, t, f32) + 1e-5f) * ldv(g, t, f32)
             + ldv(be, t, f32);
    red[t] = lrelu(bn) * ldv(W2, t, f32);
    __syncthreads();
    for (int s = 64; s > 0; s >>= 1) {
        if (t < s) red[t] += red[t + s];
        __syncthreads();
    }
    if (t == 0) stv(out, (size_t)b, f32, red[0] + ldv(b2, 0, f32));
}

// ---------------------------------------------------------------------------
extern "C" void kernel_launch(void* const* d_in, const int* in_sizes, int n_in,
                              void* d_out, int out_size, void* d_ws, size_t ws_size,
                              hipStream_t stream)
{
    (void)in_sizes; (void)n_in; (void)out_size; (void)ws_size;

    const int*  d_index = (const int*)d_in[0];
    const int*  p_index = (const int*)d_in[1];
    const void* d_vecs  = d_in[2];
    const void* p_emb   = d_in[3];
    const void* d_ecfps = d_in[4];
    const int*  d_ei    = (const int*)d_in[5];
    const void* d_ew    = d_in[6];
    const void* p_gos   = d_in[7];
    const int*  p_ei    = (const int*)d_in[8];
    const void* p_ew    = d_in[9];
    const void* d_gcn_W = d_in[10];
    const void* d_gcn_b = d_in[11];
    const void* p_gcn_W = d_in[12];
    const void* p_gcn_b = d_in[13];
    const void* enc_W1  = d_in[14];
    const void* enc_b1  = d_in[15];
    const void* enc_W2  = d_in[16];
    const void* enc_b2  = d_in[17];
    const void* dec_W1  = d_in[18];
    const void* dec_b1  = d_in[19];
    const void* dec_W2  = d_in[20];
    const void* dec_b2  = d_in[21];
    const void* out_W1  = d_in[22];
    const void* out_b1  = d_in[23];
    const void* bn_g    = d_in[24];
    const void* bn_b    = d_in[25];
    const void* bn_m    = d_in[26];
    const void* bn_v    = d_in[27];
    const void* out_W2  = d_in[28];
    const void* out_b2  = d_in[29];

    // ---- workspace carve-up ----
    char* base = (char*)d_ws;
    size_t off = 0;
    auto alloc = [&](size_t bytes) -> void* {
        void* p = base + off;
        off = (off + bytes + 255) & ~(size_t)255;
        return p;
    };
    u16* Th_d  = (u16*)alloc((size_t)1024 * 1024 * 2);
    u16* Tl_d  = (u16*)alloc((size_t)1024 * 1024 * 2);
    u16* Th_p  = (u16*)alloc((size_t)1024 * 2816 * 2);
    u16* Tl_p  = (u16*)alloc((size_t)1024 * 2816 * 2);
    u16* Th_e1 = (u16*)alloc((size_t)1024 * 3392 * 2);
    u16* Tl_e1 = (u16*)alloc((size_t)1024 * 3392 * 2);
    u16* Th_e2 = (u16*)alloc((size_t)256  * 1024 * 2);
    u16* Tl_e2 = (u16*)alloc((size_t)256  * 1024 * 2);
    u16* Th_d1 = (u16*)alloc((size_t)1024 * 256  * 2);
    u16* Tl_d1 = (u16*)alloc((size_t)1024 * 256  * 2);
    u16* Th_d2 = (u16*)alloc((size_t)3372 * 1024 * 2);
    u16* Tl_d2 = (u16*)alloc((size_t)3372 * 1024 * 2);
    float* bufA = (float*)alloc((size_t)Bsz * 1024 * 4);   // agg_d, later enc1
    float* bufB = (float*)alloc((size_t)Bsz * 2816 * 4);   // agg_p, later dec1
    float* deg_d  = (float*)alloc((size_t)ND  * 4);
    float* deg_p  = (float*)alloc((size_t)NPn * 4);
    int*   cnt_d  = (int*)alloc((size_t)ND * 4);
    int*   offs_d = (int*)alloc((size_t)(ND + 1) * 4);
    int*   cur_d  = (int*)alloc((size_t)ND * 4);
    int*   cnt_p  = (int*)alloc((size_t)NPn * 4);
    int*   offs_p = (int*)alloc((size_t)(NPn + 1) * 4);
    int*   cur_p  = (int*)alloc((size_t)NPn * 4);
    int*   crow_d = (int*)alloc((size_t)DE * 4);
    float* cw_d   = (float*)alloc((size_t)DE * 4);
    int*   crow_p = (int*)alloc((size_t)PEe * 4);
    float* cw_p   = (float*)alloc((size_t)PEe * 4);
    int*   flagp  = (int*)alloc(16);

    // ---- init ----
    detect_dtype<<<1, 64, 0, stream>>>((const u32*)d_ew, flagp);
    hipMemsetAsync(deg_d, 0, (size_t)ND * 4, stream);
    hipMemsetAsync(deg_p, 0, (size_t)NPn * 4, stream);
    hipMemsetAsync(cnt_d, 0, (size_t)ND * 4, stream);
    hipMemsetAsync(cnt_p, 0, (size_t)NPn * 4, stream);

    // ---- weight transposes + hi/lo split ----
    transpose_split<<<dim3(32, 32),  256, 0, stream>>>(d_gcn_W, Th_d,  Tl_d,  1024, 1024, 1024, flagp);
    transpose_split<<<dim3(88, 32),  256, 0, stream>>>(p_gcn_W, Th_p,  Tl_p,  2812, 1024, 2816, flagp);
    transpose_split<<<dim3(106, 32), 256, 0, stream>>>(enc_W1,  Th_e1, Tl_e1, 3372, 1024, 3392, flagp);
    transpose_split<<<dim3(32, 8),   256, 0, stream>>>(enc_W2,  Th_e2, Tl_e2, 1024, 256,  1024, flagp);
    transpose_split<<<dim3(8, 32),   256, 0, stream>>>(dec_W1,  Th_d1, Tl_d1, 256,  1024, 256,  flagp);
    transpose_split<<<dim3(32, 106), 256, 0, stream>>>(dec_W2,  Th_d2, Tl_d2, 1024, 3372, 1024, flagp);

    // ---- graph prep ----
    deg_accum<<<(DE + 255) / 256, 256, 0, stream>>>(d_ei, d_ew, deg_d, DE, flagp);
    deg_accum<<<(PEe + 255) / 256, 256, 0, stream>>>(p_ei, p_ew, deg_p, PEe, flagp);
    dinv_kernel<<<(ND + 255) / 256, 256, 0, stream>>>(deg_d, ND);
    dinv_kernel<<<(NPn + 255) / 256, 256, 0, stream>>>(deg_p, NPn);
    csr_count<<<(DE + 255) / 256, 256, 0, stream>>>(d_ei, cnt_d, DE);
    csr_count<<<(PEe + 255) / 256, 256, 0, stream>>>(p_ei, cnt_p, PEe);
    scan_kernel<<<1, 256, 0, stream>>>(cnt_d, offs_d, cur_d, ND);
    scan_kernel<<<1, 256, 0, stream>>>(cnt_p, offs_p, cur_p, NPn);
    csr_fill<<<(DE + 255) / 256, 256, 0, stream>>>(d_ei, d_ew, cur_d, crow_d, cw_d, DE, flagp);
    csr_fill<<<(PEe + 255) / 256, 256, 0, stream>>>(p_ei, p_ew, cur_p, crow_p, cw_p, PEe, flagp);

    // ---- aggregate raw X per batch row ----
    aggregate<<<Bsz, 256, 0, stream>>>(d_ecfps, 1024, 1024, d_index, deg_d,
                                       offs_d, crow_d, cw_d, flagp, bufA, 1024);
    aggregate<<<Bsz, 256, 0, stream>>>(p_gos, 2812, 2812, p_index, deg_p,
                                       offs_p, crow_p, cw_p, flagp, bufB, 2816);

    // ---- GCN linears (write directly into feature cols of d_out) ----
    gemm_split<<<dim3(8, 32), 512, 0, stream>>>(bufA, 0, 0, 1024, Th_d, Tl_d, 1024,
                                                d_out, 1, FEAT_OFF + 1324, FEAT,
                                                d_gcn_b, Bsz, 1024, 1024, 1024, 1, flagp);
    gemm_split<<<dim3(8, 32), 512, 0, stream>>>(bufB, 0, 0, 2816, Th_p, Tl_p, 2816,
                                                d_out, 1, FEAT_OFF + 2348, FEAT,
                                                p_gcn_b, Bsz, 1024, 2816, 2816, 1, flagp);

    // ---- feature cols [0,1324) ----
    concat<<<Bsz, 256, 0, stream>>>(d_vecs, p_emb, d_out, flagp);

    // ---- encoder / decoder ----
    gemm_split<<<dim3(8, 32), 512, 0, stream>>>(d_out, 1, FEAT_OFF, FEAT, Th_e1, Tl_e1, 3392,
                                                bufA, 0, 0, 1024,
                                                enc_b1, Bsz, 1024, FEAT, 3392, 1, flagp);
    gemm_split<<<dim3(2, 32), 512, 0, stream>>>(bufA, 0, 0, 1024, Th_e2, Tl_e2, 1024,
                                                d_out, 1, ENC_OFF, 256,
                                                enc_b2, Bsz, 256, 1024, 1024, 1, flagp);
    gemm_split<<<dim3(8, 32), 512, 0, stream>>>(d_out, 1, ENC_OFF, 256, Th_d1, Tl_d1, 256,
                                                bufB, 0, 0, 1024,
                                                dec_b1, Bsz, 1024, 256, 256, 1, flagp);
    gemm_split<<<dim3(27, 32), 512, 0, stream>>>(bufB, 0, 0, 1024, Th_d2, Tl_d2, 1024,
                                                 d_out, 1, DEC_OFF, FEAT,
                                                 dec_b2, Bsz, FEAT, 1024, 1024, 1, flagp);

    // ---- head ----
    head<<<Bsz, 128, 0, stream>>>(d_out, out_W1, out_b1, bn_g, bn_b,
                                  bn_m, bn_v, out_W2, out_b2, flagp);
}